// Round 1
// baseline (397.655 us; speedup 1.0000x reference)
//
#include <hip/hip_runtime.h>
#include <hip/hip_bf16.h>

typedef __bf16 bf16_t;
typedef bf16_t bf16x8 __attribute__((ext_vector_type(8)));
typedef bf16_t bf16x4 __attribute__((ext_vector_type(4)));
typedef float f32x4 __attribute__((ext_vector_type(4)));

#define SCALE 0.17677669529663687f  // 32^-0.5

// LDS strides (elements). Chosen so stride%32-dword patterns give <=2-way bank aliasing.
#define XS_S 200   // X tile rows (192 cols + pad), 400B = 25*16B aligned
#define QK_S 40    // Q/K/Oh rows (32 cols + pad), 80B
#define VT_S 168   // V-transposed rows (160 cols padded K + pad), 336B
#define P_S  168   // P rows (160 cols padded K + pad)
#define WQ_S 200   // staged Wqkv slice rows
#define WO_S 40    // staged Wout slice rows

// ---------------- prep: transpose + bf16-convert weights into workspace ----
__global__ void prep_weights(const float* __restrict__ w_qkv, const float* __restrict__ w_out,
                             bf16_t* __restrict__ wqkvT, bf16_t* __restrict__ woutT) {
    int i = blockIdx.x * 256 + threadIdx.x;
    if (i < 576 * 192) {
        int o = i / 192, k = i % 192;
        float v = w_qkv[k * 576 + o];
        if (o < 192) v *= SCALE;          // fold q-scale into Wq
        wqkvT[i] = (bf16_t)v;
    }
    if (i < 192 * 192) {
        int o = i / 192, k = i % 192;
        woutT[i] = (bf16_t)w_out[k * 192 + o];
    }
}

// ---------------- fused EarthAttention3D ----------------------------------
// grid: 992 blocks (one per (b,w)); block: 576 threads = 9 waves, wave = one
// 16-row m-tile of the 144 tokens.
__launch_bounds__(576, 3)
__global__ void earth_attn(const float* __restrict__ x, const float* __restrict__ mask,
                           const float* __restrict__ b_qkv, const float* __restrict__ bias,
                           const float* __restrict__ b_out,
                           const bf16_t* __restrict__ wqkvT, const bf16_t* __restrict__ woutT,
                           float* __restrict__ out)
{
    __shared__ bf16_t Xs[144 * XS_S];   // 57.6 KB
    __shared__ bf16_t Qb[144 * QK_S];   // 11.5 KB (reused for Oh)
    __shared__ bf16_t Kb[144 * QK_S];   // 11.5 KB
    __shared__ bf16_t VT[32 * VT_S];    // 10.75 KB
    __shared__ bf16_t Rg[144 * P_S];    // 48.4 KB shared region: WqkvS | P | WoutS

    const int bw   = blockIdx.x;        // = b*124 + w  (matches x/mask/out leading index)
    const int bb   = bw / 124;
    const int ww   = bw % 124;
    const int tid  = threadIdx.x;
    const int lane = tid & 63;
    const int wave = tid >> 6;          // 0..8
    const int lrow = lane & 15;
    const int lgrp = lane >> 4;         // 0..3
    const int t0   = wave << 4;         // this wave's token-row base

    // ---- prologue: stage X tile (fp32 -> bf16), zero VT padded-K tail ----
    const float* xp = x + (size_t)bw * (144 * 192);
    for (int u = tid; u < 144 * 48; u += 576) {
        int r = u / 48, sg = u % 48;
        const float4 v = *(const float4*)(xp + r * 192 + sg * 4);
        bf16x4 bv;
        bv[0] = (bf16_t)v.x; bv[1] = (bf16_t)v.y; bv[2] = (bf16_t)v.z; bv[3] = (bf16_t)v.w;
        *(bf16x4*)&Xs[r * XS_S + sg * 4] = bv;
    }
    if (tid < 64) {   // VT cols [144,160) = 0 so padded-K MFMA adds zero
        uint4 z = make_uint4(0, 0, 0, 0);
        *(uint4*)&VT[(tid & 31) * VT_S + 144 + (tid >> 5) * 8] = z;
    }

    f32x4 oacc[12];
#pragma unroll
    for (int i = 0; i < 12; ++i) oacc[i] = f32x4{0.f, 0.f, 0.f, 0.f};

    for (int h = 0; h < 6; ++h) {
        __syncthreads();   // Rg free (prev WoutS consumed / prologue done)

        // ---- stage Wqkv slices for head h into Rg[0..96)[WQ_S] -----------
        {
            const int bq = h * 32, bk = 192 + h * 32, bv_ = 384 + h * 32;
            for (int u = tid; u < 96 * 24; u += 576) {
                int r = u / 24, sg = u % 24;
                int sr = (r < 32) ? (bq + r) : (r < 64) ? (bk + r - 32) : (bv_ + r - 64);
                *(bf16x8*)&Rg[r * WQ_S + sg * 8] = *(const bf16x8*)(wqkvT + sr * 192 + sg * 8);
            }
        }
        __syncthreads();

        // ---- QKV projection: 16 rows x 32 cols each of Q,K,V -------------
        {
            bf16x8 xa[6];
#pragma unroll
            for (int ks = 0; ks < 6; ++ks)
                xa[ks] = *(const bf16x8*)&Xs[(t0 + lrow) * XS_S + ks * 32 + lgrp * 8];
#pragma unroll
            for (int wq = 0; wq < 3; ++wq) {
#pragma unroll
                for (int nt = 0; nt < 2; ++nt) {
                    f32x4 acc{0.f, 0.f, 0.f, 0.f};
#pragma unroll
                    for (int ks = 0; ks < 6; ++ks) {
                        bf16x8 wf = *(const bf16x8*)&Rg[(wq * 32 + nt * 16 + lrow) * WQ_S + ks * 32 + lgrp * 8];
                        acc = __builtin_amdgcn_mfma_f32_16x16x32_bf16(xa[ks], wf, acc, 0, 0, 0);
                    }
                    float bvx = b_qkv[wq * 192 + h * 32 + nt * 16 + lrow];
                    if (wq == 0) bvx *= SCALE;
                    if (wq == 2) {               // V: write transposed (VT[d][token])
                        bf16x4 pv;
#pragma unroll
                        for (int j = 0; j < 4; ++j) pv[j] = (bf16_t)(acc[j] + bvx);
                        *(bf16x4*)&VT[(nt * 16 + lrow) * VT_S + t0 + lgrp * 4] = pv;
                    } else {                     // Q / K row-major
                        bf16_t* dst = (wq == 0) ? Qb : Kb;
#pragma unroll
                        for (int j = 0; j < 4; ++j)
                            dst[(t0 + lgrp * 4 + j) * QK_S + nt * 16 + lrow] = (bf16_t)(acc[j] + bvx);
                    }
                }
            }
        }
        __syncthreads();   // K/VT visible to all waves

        // ---- S = Q K^T + bias + mask; in-register softmax; P -> Rg -------
        {
            bf16x8 qa = *(const bf16x8*)&Qb[(t0 + lrow) * QK_S + lgrp * 8];
            f32x4 s[9];
#pragma unroll
            for (int nt = 0; nt < 9; ++nt) {
                bf16x8 kb = *(const bf16x8*)&Kb[(nt * 16 + lrow) * QK_S + lgrp * 8];
                f32x4 z{0.f, 0.f, 0.f, 0.f};
                s[nt] = __builtin_amdgcn_mfma_f32_16x16x32_bf16(qa, kb, z, 0, 0, 0);
            }
            const float* bp = bias + ((size_t)(ww * 6 + h) * 144) * 144;
            const float* mp = mask + ((size_t)(bb * 124 + ww) * 144) * 144;
#pragma unroll
            for (int nt = 0; nt < 9; ++nt) {
                int m = nt * 16 + lrow;
#pragma unroll
                for (int j = 0; j < 4; ++j) {
                    int n = t0 + lgrp * 4 + j;
                    s[nt][j] += bp[n * 144 + m] + mp[n * 144 + m];
                }
            }
#pragma unroll
            for (int j = 0; j < 4; ++j) {       // row n = t0 + lgrp*4 + j
                float mx = -1e30f;
#pragma unroll
                for (int nt = 0; nt < 9; ++nt) mx = fmaxf(mx, s[nt][j]);
#pragma unroll
                for (int d = 1; d < 16; d <<= 1) mx = fmaxf(mx, __shfl_xor(mx, d, 64));
                float sum = 0.f;
#pragma unroll
                for (int nt = 0; nt < 9; ++nt) { float e = __expf(s[nt][j] - mx); s[nt][j] = e; sum += e; }
#pragma unroll
                for (int d = 1; d < 16; d <<= 1) sum += __shfl_xor(sum, d, 64);
                float rinv = 1.0f / sum;
#pragma unroll
                for (int nt = 0; nt < 9; ++nt) s[nt][j] *= rinv;
            }
#pragma unroll
            for (int nt = 0; nt < 9; ++nt)
#pragma unroll
                for (int j = 0; j < 4; ++j)
                    Rg[(t0 + lgrp * 4 + j) * P_S + nt * 16 + lrow] = (bf16_t)s[nt][j];
            // zero this wave's P tail cols [144,160)
            uint2 z2 = make_uint2(0u, 0u);
            *(uint2*)&Rg[(t0 + lrow) * P_S + 144 + lgrp * 4] = z2;
        }
        // (no barrier: each wave reads only its own P rows; VT already fenced)

        // ---- O_h = P @ V ; write to Qb (own rows, Q is dead) --------------
        {
            f32x4 o0{0.f, 0.f, 0.f, 0.f}, o1{0.f, 0.f, 0.f, 0.f};
#pragma unroll
            for (int ks = 0; ks < 5; ++ks) {
                bf16x8 pa = *(const bf16x8*)&Rg[(t0 + lrow) * P_S + ks * 32 + lgrp * 8];
                bf16x8 v0 = *(const bf16x8*)&VT[(lrow) * VT_S + ks * 32 + lgrp * 8];
                bf16x8 v1 = *(const bf16x8*)&VT[(16 + lrow) * VT_S + ks * 32 + lgrp * 8];
                o0 = __builtin_amdgcn_mfma_f32_16x16x32_bf16(pa, v0, o0, 0, 0, 0);
                o1 = __builtin_amdgcn_mfma_f32_16x16x32_bf16(pa, v1, o1, 0, 0, 0);
            }
#pragma unroll
            for (int j = 0; j < 4; ++j) {
                Qb[(t0 + lgrp * 4 + j) * QK_S + lrow]      = (bf16_t)o0[j];
                Qb[(t0 + lgrp * 4 + j) * QK_S + 16 + lrow] = (bf16_t)o1[j];
            }
        }
        __syncthreads();   // all waves done reading P before Rg reuse

        // ---- stage Wout k-slice (rows h*32..h*32+31 of w_out) -------------
        for (int u = tid; u < 192 * 4; u += 576) {
            int r = u >> 2, sg = u & 3;
            *(bf16x8*)&Rg[r * WO_S + sg * 8] = *(const bf16x8*)(woutT + r * 192 + h * 32 + sg * 8);
        }
        __syncthreads();

        // ---- partial out-projection: oacc += O_h @ Wout[h*32:+32, :] ------
        {
            bf16x8 oa = *(const bf16x8*)&Qb[(t0 + lrow) * QK_S + lgrp * 8];
#pragma unroll
            for (int oc = 0; oc < 12; ++oc) {
                bf16x8 wf = *(const bf16x8*)&Rg[(oc * 16 + lrow) * WO_S + lgrp * 8];
                oacc[oc] = __builtin_amdgcn_mfma_f32_16x16x32_bf16(oa, wf, oacc[oc], 0, 0, 0);
            }
        }
    }

    // ---- epilogue: + b_out, store fp32 -----------------------------------
    float* op = out + (size_t)bw * (144 * 192);
#pragma unroll
    for (int oc = 0; oc < 12; ++oc) {
        int c = oc * 16 + lrow;
        float bo = b_out[c];
#pragma unroll
        for (int j = 0; j < 4; ++j)
            op[(t0 + lgrp * 4 + j) * 192 + c] = oacc[oc][j] + bo;
    }
}

extern "C" void kernel_launch(void* const* d_in, const int* in_sizes, int n_in,
                              void* d_out, int out_size, void* d_ws, size_t ws_size,
                              hipStream_t stream) {
    const float* x     = (const float*)d_in[0];
    const float* mask  = (const float*)d_in[1];
    const float* w_qkv = (const float*)d_in[2];
    const float* b_qkv = (const float*)d_in[3];
    const float* bias  = (const float*)d_in[4];
    const float* w_out = (const float*)d_in[5];
    const float* b_out = (const float*)d_in[6];

    bf16_t* wqkvT = (bf16_t*)d_ws;                 // 576*192 bf16
    bf16_t* woutT = wqkvT + 576 * 192;             // 192*192 bf16   (total 294,912 B)

    prep_weights<<<dim3((576 * 192 + 255) / 256), dim3(256), 0, stream>>>(w_qkv, w_out, wqkvT, woutT);
    earth_attn<<<dim3(992), dim3(576), 0, stream>>>(x, mask, b_qkv, bias, b_out, wqkvT, woutT,
                                                    (float*)d_out);
}